// Round 1
// baseline (715.402 us; speedup 1.0000x reference)
//
#include <hip/hip_runtime.h>

#define DIM 128
#define NUM_GRAPHS 512

// ---------------------------------------------------------------------------
// Segment-sum of x over sorted contiguous `batch` ids.
// Thread layout: 256 threads = 8 node-groups x 32 float4 dim-chunks.
// Each thread walks 64 contiguous nodes, accumulating one float4 of the row
// in registers; flushes to global sums with atomicAdd only when the graph id
// changes (graphs are ~1953 nodes, so <=2 flushes per thread).
// Reads are fully coalesced: 32 consecutive threads read one 512B row.
// ---------------------------------------------------------------------------
__global__ __launch_bounds__(256) void seg_sum_kernel(
    const float* __restrict__ x, const int* __restrict__ batch,
    float* __restrict__ sums, float* __restrict__ counts, int n_nodes)
{
    const int NODES_PER_GROUP = 64;             // nodes per thread
    int chunk = threadIdx.x & 31;               // which float4 of the 128-dim row
    int group = threadIdx.x >> 5;               // which node-run within the block
    long long node0 = (long long)blockIdx.x * 512 + (long long)group * NODES_PER_GROUP;
    const float4* __restrict__ xv = (const float4*)x;

    float4 acc = make_float4(0.f, 0.f, 0.f, 0.f);
    int cur_g = -1;
    float run = 0.f;

    for (int i = 0; i < NODES_PER_GROUP; ++i) {
        long long node = node0 + i;
        if (node >= n_nodes) break;
        int g = batch[node];                    // broadcast within the 32-lane row
        if (g != cur_g) {
            if (cur_g >= 0) {
                float* s = sums + (long long)cur_g * DIM + chunk * 4;
                atomicAdd(s + 0, acc.x); atomicAdd(s + 1, acc.y);
                atomicAdd(s + 2, acc.z); atomicAdd(s + 3, acc.w);
                if (chunk == 0) atomicAdd(counts + cur_g, run);
            }
            cur_g = g;
            acc = make_float4(0.f, 0.f, 0.f, 0.f);
            run = 0.f;
        }
        float4 v = xv[node * 32 + chunk];
        acc.x += v.x; acc.y += v.y; acc.z += v.z; acc.w += v.w;
        run += 1.f;
    }
    if (cur_g >= 0) {
        float* s = sums + (long long)cur_g * DIM + chunk * 4;
        atomicAdd(s + 0, acc.x); atomicAdd(s + 1, acc.y);
        atomicAdd(s + 2, acc.z); atomicAdd(s + 3, acc.w);
        if (chunk == 0) atomicAdd(counts + cur_g, run);
    }
}

// ---------------------------------------------------------------------------
// pooled = (sums/counts) @ W1 @ W2 + (b1 @ W2 + b2), computed per graph row.
// Exploits linearity: mean commutes past the (activation-free) MLP.
// One block per graph, one thread per output dim. 33 MFLOP total — trivial.
// ---------------------------------------------------------------------------
__global__ __launch_bounds__(DIM) void mlp_kernel(
    const float* __restrict__ sums, const float* __restrict__ counts,
    const float* __restrict__ W1, const float* __restrict__ b1,
    const float* __restrict__ W2, const float* __restrict__ b2,
    float* __restrict__ out)
{
    __shared__ float xrow[DIM];
    __shared__ float yrow[DIM];
    int g = blockIdx.x;
    int t = threadIdx.x;
    float inv_cnt = 1.0f / counts[g];
    xrow[t] = sums[(long long)g * DIM + t] * inv_cnt;
    __syncthreads();
    float acc = b1[t];
    #pragma unroll 8
    for (int k = 0; k < DIM; ++k) acc += xrow[k] * W1[k * DIM + t];  // coalesced W1 read
    yrow[t] = acc;
    __syncthreads();
    float acc2 = b2[t];
    #pragma unroll 8
    for (int k = 0; k < DIM; ++k) acc2 += yrow[k] * W2[k * DIM + t];
    out[(long long)g * DIM + t] = acc2;
}

// ---------------------------------------------------------------------------
// int32 -> float32 copy (edge_index and batch pass-through outputs).
// Vectorized int4 -> float4; scalar tail handled by thread 0 of block 0.
// ---------------------------------------------------------------------------
__global__ __launch_bounds__(256) void copy_i2f(
    const int* __restrict__ src, float* __restrict__ dst, long long n)
{
    long long i4 = (long long)blockIdx.x * blockDim.x + threadIdx.x;
    long long n4 = n >> 2;
    if (i4 < n4) {
        int4 v = ((const int4*)src)[i4];
        ((float4*)dst)[i4] = make_float4((float)v.x, (float)v.y, (float)v.z, (float)v.w);
    }
    if (i4 == 0) {
        for (long long j = n4 << 2; j < n; ++j) dst[j] = (float)src[j];
    }
}

extern "C" void kernel_launch(void* const* d_in, const int* in_sizes, int n_in,
                              void* d_out, int out_size, void* d_ws, size_t ws_size,
                              hipStream_t stream) {
    const float* x     = (const float*)d_in[0];
    const int*   edge  = (const int*)d_in[1];
    const int*   batch = (const int*)d_in[2];
    const float* W1    = (const float*)d_in[3];
    const float* b1    = (const float*)d_in[4];
    const float* W2    = (const float*)d_in[5];
    const float* b2    = (const float*)d_in[6];
    float* out = (float*)d_out;

    long long edge_n  = in_sizes[1];   // 4,000,000 int32
    long long n_nodes = in_sizes[2];   // 1,000,000

    float* sums   = (float*)d_ws;                       // [NUM_GRAPHS, DIM]
    float* counts = sums + (size_t)NUM_GRAPHS * DIM;    // [NUM_GRAPHS]

    // ws is poisoned 0xAA each timed call — zero the accumulators.
    hipMemsetAsync(d_ws, 0, ((size_t)NUM_GRAPHS * DIM + NUM_GRAPHS) * sizeof(float), stream);

    int blocksA = (int)((n_nodes + 511) / 512);
    seg_sum_kernel<<<blocksA, 256, 0, stream>>>(x, batch, sums, counts, (int)n_nodes);

    mlp_kernel<<<NUM_GRAPHS, DIM, 0, stream>>>(sums, counts, W1, b1, W2, b2, out);

    // Pass-through outputs (written as float32 into the flat out buffer).
    float* edge_out  = out + (size_t)NUM_GRAPHS * DIM;
    float* batch_out = edge_out + edge_n;
    {
        long long n4 = edge_n >> 2;
        int blocks = (int)((n4 + 255) / 256);
        copy_i2f<<<blocks, 256, 0, stream>>>(edge, edge_out, edge_n);
    }
    {
        long long n4 = n_nodes >> 2;
        int blocks = (int)((n4 + 255) / 256);
        copy_i2f<<<blocks, 256, 0, stream>>>(batch, batch_out, n_nodes);
    }
}

// Round 2
// 702.537 us; speedup vs baseline: 1.0183x; 1.0183x over previous
//
#include <hip/hip_runtime.h>

#define DIM 128
#define NUM_GRAPHS 512

typedef float f4 __attribute__((ext_vector_type(4)));

__device__ __forceinline__ void flush_acc(float* __restrict__ sums,
                                          float* __restrict__ counts,
                                          int g, int chunk, f4 a, float run) {
    float* s = sums + (size_t)g * DIM + chunk * 4;
    atomicAdd(s + 0, a[0]); atomicAdd(s + 1, a[1]);
    atomicAdd(s + 2, a[2]); atomicAdd(s + 3, a[3]);
    if (chunk == 0) atomicAdd(counts + g, run);
}

// ---------------------------------------------------------------------------
// Segment-sum of x over sorted contiguous `batch`.
// 256 threads = 8 node-runs x 32 float4 dim-chunks; each thread owns 64
// contiguous nodes. Segments are ~1953 nodes, so a 64-node run crosses at
// most one boundary: test endpoints only, branch-free unrolled fast path
// (nontemporal float4 stream, 2 accumulators), binary search for the split
// in the boundary case, scalar fallback if >1 boundary (never in this data).
// ---------------------------------------------------------------------------
__global__ __launch_bounds__(256) void seg_sum_kernel(
    const float* __restrict__ x, const int* __restrict__ batch,
    float* __restrict__ sums, float* __restrict__ counts, int n_nodes)
{
    const int NPT = 64;                          // nodes per thread
    int chunk = threadIdx.x & 31;
    int group = threadIdx.x >> 5;
    long long node0 = (long long)blockIdx.x * 512 + (long long)group * NPT;
    if (node0 >= n_nodes) return;
    int cnt = NPT;
    if (node0 + NPT > n_nodes) cnt = (int)(n_nodes - node0);

    const f4* __restrict__ xv = (const f4*)x;
    const f4* __restrict__ p = xv + node0 * 32 + chunk;   // stride 32 f4 per node

    int g0 = batch[node0];
    int g1 = batch[node0 + cnt - 1];

    if (g0 == g1) {
        // fast path: whole run in one segment — pure pipelined stream
        f4 a = (f4)0.f, b = (f4)0.f;
        int i = 0;
        #pragma unroll 4
        for (; i + 1 < cnt; i += 2) {
            f4 v0 = __builtin_nontemporal_load(p + (long long)i * 32);
            f4 v1 = __builtin_nontemporal_load(p + (long long)(i + 1) * 32);
            a += v0; b += v1;
        }
        if (i < cnt) a += __builtin_nontemporal_load(p + (long long)i * 32);
        flush_acc(sums, counts, g0, chunk, a + b, (float)cnt);
    } else if (g1 - g0 == 1) {
        // exactly one boundary: binary search (batch is sorted)
        int lo = 1, hi = cnt - 1;
        while (lo < hi) {
            int mid = (lo + hi) >> 1;
            if (batch[node0 + mid] == g0) lo = mid + 1; else hi = mid;
        }
        f4 a = (f4)0.f;
        for (int i = 0; i < lo; ++i)
            a += __builtin_nontemporal_load(p + (long long)i * 32);
        flush_acc(sums, counts, g0, chunk, a, (float)lo);
        a = (f4)0.f;
        for (int i = lo; i < cnt; ++i)
            a += __builtin_nontemporal_load(p + (long long)i * 32);
        flush_acc(sums, counts, g1, chunk, a, (float)(cnt - lo));
    } else {
        // generic fallback (segments shorter than a run) — never hit here
        f4 a = (f4)0.f;
        int cur = g0; float run = 0.f;
        for (int i = 0; i < cnt; ++i) {
            int g = batch[node0 + i];
            if (g != cur) {
                flush_acc(sums, counts, cur, chunk, a, run);
                cur = g; a = (f4)0.f; run = 0.f;
            }
            a += __builtin_nontemporal_load(p + (long long)i * 32);
            run += 1.f;
        }
        flush_acc(sums, counts, cur, chunk, a, run);
    }
}

// ---------------------------------------------------------------------------
// pooled = (sums/counts) @ W1 @ W2 + (b1 @ W2 + b2).
// Linearity: mean commutes past the activation-free MLP. 33 MFLOP — trivial.
// ---------------------------------------------------------------------------
__global__ __launch_bounds__(DIM) void mlp_kernel(
    const float* __restrict__ sums, const float* __restrict__ counts,
    const float* __restrict__ W1, const float* __restrict__ b1,
    const float* __restrict__ W2, const float* __restrict__ b2,
    float* __restrict__ out)
{
    __shared__ float xrow[DIM];
    __shared__ float yrow[DIM];
    int g = blockIdx.x;
    int t = threadIdx.x;
    float inv_cnt = 1.0f / counts[g];
    xrow[t] = sums[(size_t)g * DIM + t] * inv_cnt;
    __syncthreads();
    float acc = b1[t];
    #pragma unroll 8
    for (int k = 0; k < DIM; ++k) acc += xrow[k] * W1[k * DIM + t];
    yrow[t] = acc;
    __syncthreads();
    float acc2 = b2[t];
    #pragma unroll 8
    for (int k = 0; k < DIM; ++k) acc2 += yrow[k] * W2[k * DIM + t];
    out[(size_t)g * DIM + t] = acc2;
}

// ---------------------------------------------------------------------------
// Merged int32 -> float32 pass-through copies (edge_index then batch),
// one dispatch, int4 -> float4 vectorized. Both sizes divisible by 4.
// ---------------------------------------------------------------------------
__global__ __launch_bounds__(256) void copy2_i2f(
    const int4* __restrict__ e, float4* __restrict__ eo, long long ne4,
    const int4* __restrict__ b, float4* __restrict__ bo, long long nb4)
{
    long long i = (long long)blockIdx.x * blockDim.x + threadIdx.x;
    if (i < ne4) {
        int4 v = e[i];
        eo[i] = make_float4((float)v.x, (float)v.y, (float)v.z, (float)v.w);
    } else {
        long long j = i - ne4;
        if (j < nb4) {
            int4 v = b[j];
            bo[j] = make_float4((float)v.x, (float)v.y, (float)v.z, (float)v.w);
        }
    }
}

extern "C" void kernel_launch(void* const* d_in, const int* in_sizes, int n_in,
                              void* d_out, int out_size, void* d_ws, size_t ws_size,
                              hipStream_t stream) {
    const float* x     = (const float*)d_in[0];
    const int*   edge  = (const int*)d_in[1];
    const int*   batch = (const int*)d_in[2];
    const float* W1    = (const float*)d_in[3];
    const float* b1    = (const float*)d_in[4];
    const float* W2    = (const float*)d_in[5];
    const float* b2    = (const float*)d_in[6];
    float* out = (float*)d_out;

    long long edge_n  = in_sizes[1];   // 4,000,000 int32
    long long n_nodes = in_sizes[2];   // 1,000,000

    float* sums   = (float*)d_ws;                       // [NUM_GRAPHS, DIM]
    float* counts = sums + (size_t)NUM_GRAPHS * DIM;    // [NUM_GRAPHS]

    // ws is poisoned 0xAA each timed call — zero the accumulators.
    hipMemsetAsync(d_ws, 0, ((size_t)NUM_GRAPHS * DIM + NUM_GRAPHS) * sizeof(float), stream);

    int blocksA = (int)((n_nodes + 511) / 512);
    seg_sum_kernel<<<blocksA, 256, 0, stream>>>(x, batch, sums, counts, (int)n_nodes);

    mlp_kernel<<<NUM_GRAPHS, DIM, 0, stream>>>(sums, counts, W1, b1, W2, b2, out);

    // Pass-through outputs (flat float32 in d_out after pooled).
    float* edge_out  = out + (size_t)NUM_GRAPHS * DIM;
    float* batch_out = edge_out + edge_n;
    long long ne4 = edge_n >> 2, nb4 = n_nodes >> 2;
    int blocksC = (int)((ne4 + nb4 + 255) / 256);
    copy2_i2f<<<blocksC, 256, 0, stream>>>((const int4*)edge, (float4*)edge_out, ne4,
                                           (const int4*)batch, (float4*)batch_out, nb4);
}